// Round 6
// baseline (140.011 us; speedup 1.0000x reference)
//
#include <hip/hip_runtime.h>
#include <math.h>

// Cosine similarity per matching row: out[r] = dot(a[r,:], b[r,:]) /
// (||a[r,:]|| * ||b[r,:]||), D = 256 floats per row, eps-guarded.
//
// Round-10: last untested lever before declaring the read roofline —
// a persistent NEVER-DRAIN pipeline (T3/T4 counted-vmcnt applied to a
// streaming reduce). Every prior variant (2-deep serial r5, burst+vmcnt(0)
// r6, nt r0/r9) periodically drains outstanding loads to zero during the
// reduce / block-churn windows. This kernel never does:
//  - 1024 blocks x 4 waves, exactly resident (4 blocks/CU), zero churn;
//    each wave owns 16 rows = 4 iterations x 4 rows, register double-buffered.
//  - per iteration: issue NEXT iter's 8 x global_load_dwordx4 nt (asm,
//    order-guaranteed), s_waitcnt vmcnt(8) -- waits only for the PREVIOUS
//    iter's 8 loads, current prefetch stays in flight -- sched_barrier(0)
//    fence (rule #18: "memory" clobber doesn't order register-only
//    consumers), then reduce.
//  - loads in flight 100% of kernel time; chip-wide in-flight ~32 MB >> BDP.
// If this still lands at ~3.3 TB/s read, the inbound-fabric cap is confirmed
// by five structurally independent kernels and the roofline is declared.

#define EPS 1e-12f

typedef float f4 __attribute__((ext_vector_type(4)));

#define GLOADNT(dst, voff, sbase, imm)                                   \
    asm volatile("global_load_dwordx4 %0, %1, %2 offset:" #imm " nt"     \
                 : "=&v"(dst) : "v"(voff), "s"(sbase) : "memory")

#define VMWAIT(n)                                                        \
    do {                                                                 \
        asm volatile("s_waitcnt vmcnt(" #n ")" ::: "memory");            \
        __builtin_amdgcn_sched_barrier(0);                               \
    } while (0)

#define ROW_REDUCE_STORE(av, bv, ridx)                                     \
    do {                                                                   \
        float saa = av.x * av.x + av.y * av.y + av.z * av.z + av.w * av.w; \
        float sbb = bv.x * bv.x + bv.y * bv.y + bv.z * bv.z + bv.w * bv.w; \
        float sab = av.x * bv.x + av.y * bv.y + av.z * bv.z + av.w * bv.w; \
        _Pragma("unroll")                                                  \
        for (int off = 32; off > 0; off >>= 1) {                           \
            saa += __shfl_xor(saa, off, 64);                               \
            sbb += __shfl_xor(sbb, off, 64);                               \
            sab += __shfl_xor(sab, off, 64);                               \
        }                                                                  \
        if (lane == 0) {                                                   \
            const float denom =                                            \
                sqrtf(fmaxf(saa, EPS)) * sqrtf(fmaxf(sbb, EPS));           \
            out[base + (ridx)] = sab / denom;                              \
        }                                                                  \
    } while (0)

__global__ __launch_bounds__(256, 4) void cosine_rows_kernel(
    const float* __restrict__ a,
    const float* __restrict__ b,
    float* __restrict__ out,
    int nrows)
{
    const int lane = threadIdx.x & 63;
    const int wid  = (blockIdx.x << 2) + (threadIdx.x >> 6);  // 0..4095
    const int base = wid << 4;                                // 16 rows/wave
    if (base >= nrows) return;

    // byte voffsets: row stride 1024 B, lane covers 16 B, iter stride 4 KiB
    const unsigned v0 = ((unsigned)wid << 14) + ((unsigned)lane << 4);
    const unsigned v1 = v0 + 4096u;
    const unsigned v2 = v0 + 8192u;
    const unsigned v3 = v0 + 12288u;

    f4 aA0, aA1, aA2, aA3, bA0, bA1, bA2, bA3;  // buffer A (even iters)
    f4 aB0, aB1, aB2, aB3, bB0, bB1, bB2, bB3;  // buffer B (odd iters)

    // ---- prologue: issue iter 0 (buffer A) ----
    GLOADNT(aA0, v0, a, 0);    GLOADNT(aA1, v0, a, 1024);
    GLOADNT(aA2, v0, a, 2048); GLOADNT(aA3, v0, a, 3072);
    GLOADNT(bA0, v0, b, 0);    GLOADNT(bA1, v0, b, 1024);
    GLOADNT(bA2, v0, b, 2048); GLOADNT(bA3, v0, b, 3072);

    // ---- issue iter 1 (buffer B); wait iter 0; reduce A ----
    GLOADNT(aB0, v1, a, 0);    GLOADNT(aB1, v1, a, 1024);
    GLOADNT(aB2, v1, a, 2048); GLOADNT(aB3, v1, a, 3072);
    GLOADNT(bB0, v1, b, 0);    GLOADNT(bB1, v1, b, 1024);
    GLOADNT(bB2, v1, b, 2048); GLOADNT(bB3, v1, b, 3072);
    VMWAIT(8);
    ROW_REDUCE_STORE(aA0, bA0, 0);
    ROW_REDUCE_STORE(aA1, bA1, 1);
    ROW_REDUCE_STORE(aA2, bA2, 2);
    ROW_REDUCE_STORE(aA3, bA3, 3);

    // ---- issue iter 2 (buffer A); wait iter 1 (+stores); reduce B ----
    GLOADNT(aA0, v2, a, 0);    GLOADNT(aA1, v2, a, 1024);
    GLOADNT(aA2, v2, a, 2048); GLOADNT(aA3, v2, a, 3072);
    GLOADNT(bA0, v2, b, 0);    GLOADNT(bA1, v2, b, 1024);
    GLOADNT(bA2, v2, b, 2048); GLOADNT(bA3, v2, b, 3072);
    VMWAIT(8);
    ROW_REDUCE_STORE(aB0, bB0, 4);
    ROW_REDUCE_STORE(aB1, bB1, 5);
    ROW_REDUCE_STORE(aB2, bB2, 6);
    ROW_REDUCE_STORE(aB3, bB3, 7);

    // ---- issue iter 3 (buffer B); wait iter 2 (+stores); reduce A ----
    GLOADNT(aB0, v3, a, 0);    GLOADNT(aB1, v3, a, 1024);
    GLOADNT(aB2, v3, a, 2048); GLOADNT(aB3, v3, a, 3072);
    GLOADNT(bB0, v3, b, 0);    GLOADNT(bB1, v3, b, 1024);
    GLOADNT(bB2, v3, b, 2048); GLOADNT(bB3, v3, b, 3072);
    VMWAIT(8);
    ROW_REDUCE_STORE(aA0, bA0, 8);
    ROW_REDUCE_STORE(aA1, bA1, 9);
    ROW_REDUCE_STORE(aA2, bA2, 10);
    ROW_REDUCE_STORE(aA3, bA3, 11);

    // ---- epilogue: wait iter 3; reduce B ----
    VMWAIT(0);
    ROW_REDUCE_STORE(aB0, bB0, 12);
    ROW_REDUCE_STORE(aB1, bB1, 13);
    ROW_REDUCE_STORE(aB2, bB2, 14);
    ROW_REDUCE_STORE(aB3, bB3, 15);
}

extern "C" void kernel_launch(void* const* d_in, const int* in_sizes, int n_in,
                              void* d_out, int out_size, void* d_ws, size_t ws_size,
                              hipStream_t stream) {
    const float* a = (const float*)d_in[0];
    const float* b = (const float*)d_in[1];
    float* out = (float*)d_out;

    const int nrows = out_size;   // 16 * 4096 = 65536
    const int blocks = 1024;      // 4096 waves x 16 rows = 65536; 4 blocks/CU,
                                  // exactly resident -> persistent, zero churn

    cosine_rows_kernel<<<blocks, 256, 0, stream>>>(a, b, out, nrows);
}

// Round 7
// 136.270 us; speedup vs baseline: 1.0275x; 1.0275x over previous
//
#include <hip/hip_runtime.h>
#include <math.h>

// Cosine similarity per matching row: out[r] = dot(a[r,:], b[r,:]) /
// (||a[r,:]|| * ||b[r,:]||), D = 256 floats per row, eps-guarded.
//
// Round-11: FINAL — restore the roofline-confirmed best configuration
// (benched 136.77us and 136.70us scored; kernel <=40.4us).
//
// Roofline argument (5 structurally independent kernels):
//   read BW beyond-L2 caps at ~3.3-3.4 TB/s chip-wide regardless of
//   structure: compiler-serial/58%occ=3.05, 16-deep-asm/38%occ=3.01,
//   nt/8-deep=3.36, strided-nt=2.8(eff), persistent never-drain
//   vmcnt(8) pipeline=3.2. Meanwhile write-only fills sustain 6.6 TB/s
//   and copy (m13) = 6.29 = 3.15R+3.15W -> per-direction budget.
//   50% L3-hit service raised read BW by zero (L3 is memory-side MALL;
//   hits cross the same inbound path as HBM).
//   Floor for the irreducible 134.2 MB single-pass read: ~40us.
//   This kernel measures <=40.4us = within ~1% of the floor.
//   Falsified as levers: MLP depth, occupancy, reduction cost, L3
//   residency, issue-drain windows, block churn.
//
// Config notes:
//  - 1 wave per row-quad per iteration: 8 contiguous 1 KiB wave-loads
//    (4 rows x {a,b}) issued back-to-back (fully coalesced: 64 lanes x 16 B).
//  - __builtin_nontemporal_load measurably best (~3.36 vs ~3.05 TB/s).
//  - 2048 blocks x 256 threads, plain launch bounds: 8 waves/SIMD.

#define EPS 1e-12f

typedef float f4 __attribute__((ext_vector_type(4)));

__global__ __launch_bounds__(256) void cosine_rows_kernel(
    const f4* __restrict__ a4,
    const f4* __restrict__ b4,
    float* __restrict__ out,
    int nrows)
{
    const int lane = threadIdx.x & 63;
    const int wid  = (blockIdx.x << 2) + (threadIdx.x >> 6);
    const int nw   = gridDim.x << 2;

    for (int base = wid * 4; base < nrows; base += nw * 4) {
        // 8 independent 1 KiB wave-loads, all issued before any use.
        const int i0 = (base + 0) * 64 + lane;
        const int i1 = (base + 1) * 64 + lane;
        const int i2 = (base + 2) * 64 + lane;
        const int i3 = (base + 3) * 64 + lane;
        f4 av0 = __builtin_nontemporal_load(&a4[i0]);
        f4 av1 = __builtin_nontemporal_load(&a4[i1]);
        f4 av2 = __builtin_nontemporal_load(&a4[i2]);
        f4 av3 = __builtin_nontemporal_load(&a4[i3]);
        f4 bv0 = __builtin_nontemporal_load(&b4[i0]);
        f4 bv1 = __builtin_nontemporal_load(&b4[i1]);
        f4 bv2 = __builtin_nontemporal_load(&b4[i2]);
        f4 bv3 = __builtin_nontemporal_load(&b4[i3]);

        f4 avs[4] = {av0, av1, av2, av3};
        f4 bvs[4] = {bv0, bv1, bv2, bv3};

        #pragma unroll
        for (int r = 0; r < 4; ++r) {
            const f4 av = avs[r];
            const f4 bv = bvs[r];
            float saa = av.x * av.x + av.y * av.y + av.z * av.z + av.w * av.w;
            float sbb = bv.x * bv.x + bv.y * bv.y + bv.z * bv.z + bv.w * bv.w;
            float sab = av.x * bv.x + av.y * bv.y + av.z * bv.z + av.w * bv.w;

            #pragma unroll
            for (int off = 32; off > 0; off >>= 1) {
                saa += __shfl_xor(saa, off, 64);
                sbb += __shfl_xor(sbb, off, 64);
                sab += __shfl_xor(sab, off, 64);
            }

            if (lane == 0) {
                const float denom = sqrtf(fmaxf(saa, EPS)) * sqrtf(fmaxf(sbb, EPS));
                out[base + r] = sab / denom;
            }
        }
    }
}

extern "C" void kernel_launch(void* const* d_in, const int* in_sizes, int n_in,
                              void* d_out, int out_size, void* d_ws, size_t ws_size,
                              hipStream_t stream) {
    const float* a = (const float*)d_in[0];
    const float* b = (const float*)d_in[1];
    float* out = (float*)d_out;

    const int nrows = out_size;   // 16 * 4096 = 65536 (divisible by 4)
    const int blocks = 2048;      // 8 blocks/CU target; 2 sweeps per wave

    cosine_rows_kernel<<<blocks, 256, 0, stream>>>(
        (const f4*)a, (const f4*)b, out, nrows);
}